// Round 11
// baseline (5154.247 us; speedup 1.0000x reference)
//
#include <hip/hip_runtime.h>
#include <cstdint>
#include <cstddef>

// Problem dims
#define NB 16
#define NT 1024
#define NE 1024
#define NS 256
#define ND 512
#define NH 128
#define T0 16

// ---- ws layout (float offsets) ----
#define OFF_US   ((size_t)0)          // us [m][t][s]; scan overwrites in-place as xs
#define OFF_HU   ((size_t)4194304)
#define OFF_U3   ((size_t)8388608)
#define OFF_KT   ((size_t)12582912)
#define OFF_HT   ((size_t)12845056)
#define OFF_AT   ((size_t)12976128)
#define OFF_G    ((size_t)13041664)
#define OFF_IG   ((size_t)13107200)
#define OFF_MINF ((size_t)13172736)
#define OFF_WZT  ((size_t)13238272)
#define OFF_WRT  ((size_t)13287424)
#define OFF_WHT  ((size_t)13336576)
#define OFF_HTWO ((size_t)13385728)   // 256*1024
#define OFF_WG   ((size_t)13647872)   // 256*384
#define OFF_BG   ((size_t)13746176)   // 384 (pad 512)
#define OFF_MG   ((size_t)13746688)   // 256*384
#define OFF_PACK ((size_t)13844992)   // 1622016 shorts -> ws end 14656000 fl (58.6MB)

// pack sub-offsets (shorts)
#define PK_A   0
#define PK_G   65536
#define PK_M   131072
#define PK_Z   196608
#define PK_R   245760
#define PK_H   294912
#define PK_O   344064
#define PK_WIN 376832
#define PK_WST 901120
#define PK_HM  1032192
#define PK_HTW 1163264
#define PK_MG  1425408
#define PK_WG  1523712

// d_out scratch (floats): usG [4.19M..8.39M) (dead after k_fuse), then ug [0..6.29M);
//                         u f32 [8.39M..16.78M) (dead after us/Hu). Final GEMM overwrites all.

typedef short bf16x8 __attribute__((ext_vector_type(8)));
typedef float f32x4 __attribute__((ext_vector_type(4)));
typedef unsigned int u32x2 __attribute__((ext_vector_type(2)));

#define MFMA(a, b, c) __builtin_amdgcn_mfma_f32_16x16x32_bf16((a), (b), (c), 0, 0, 0)

// barrier WITHOUT vmcnt drain
#define SYNCW() do { \
    __builtin_amdgcn_sched_barrier(0); \
    asm volatile("s_waitcnt lgkmcnt(0)" ::: "memory"); \
    __builtin_amdgcn_s_barrier(); \
    __builtin_amdgcn_sched_barrier(0); \
} while (0)

__device__ __forceinline__ float gelu_tanh(float v) {
    const float c = 0.7978845608028654f;
    float t = tanhf(c * (v + 0.044715f * v * v * v));
    return 0.5f * v * (1.0f + t);
}
__device__ __forceinline__ float softplus_f(float x) {
    if (x > 20.0f) return x;
    return log1pf(expf(x));
}
__device__ __forceinline__ short f2bf_s(float f) {
    unsigned u = __float_as_uint(f);
    u += 0x7fffu + ((u >> 16) & 1u);
    return (short)(u >> 16);
}
__device__ __forceinline__ unsigned pk_bf(float a, float b) {
    return ((unsigned)(unsigned short)f2bf_s(b) << 16) | (unsigned)(unsigned short)f2bf_s(a);
}
__device__ __forceinline__ float exp2_hw(float x) {
    float r; asm("v_exp_f32 %0, %1" : "=v"(r) : "v"(x)); return r;
}
__device__ __forceinline__ float rcp_hw(float x) {
    float r; asm("v_rcp_f32 %0, %1" : "=v"(r) : "v"(x)); return r;
}
__device__ __forceinline__ f32x4 sig4(f32x4 x) {
    f32x4 o;
#pragma unroll
    for (int i = 0; i < 4; ++i)
        o[i] = rcp_hw(1.0f + exp2_hw(-1.442695040888963f * x[i]));
    return o;
}
__device__ __forceinline__ f32x4 tanh4(f32x4 x) {
    f32x4 o;
#pragma unroll
    for (int i = 0; i < 4; ++i) {
        float e = exp2_hw(2.885390081777927f * x[i]);
        o[i] = 1.0f - 2.0f * rcp_hw(e + 1.0f);
    }
    return o;
}
__device__ __forceinline__ void st_bf4(char* base, int stride, int row, int byteoff,
                                       const f32x4& v) {
    u32x2 p;
    p[0] = pk_bf(v[0], v[1]);
    p[1] = pk_bf(v[2], v[3]);
    *(u32x2*)(base + row * stride + byteoff) = p;
}

#define BFRAG(buf, STR, ks) (*(const bf16x8*)((buf) + (l & 15) * (STR) + (ks) * 64 + (l >> 4) * 16))
#define GFRAG(p, fi) (*(const bf16x8*)((p) + ((size_t)(fi) * 64 + l) * 8))
#define LFRAG(buf, fi) (*(const bf16x8*)((buf) + (size_t)(fi) * 1024 + l * 16))

// ---- P/K covariance recurrence ----
__global__ __launch_bounds__(512) void k_precompute(const float* __restrict__ Q,
                                                    const float* __restrict__ R,
                                                    float* __restrict__ Kt) {
    __shared__ float red[512];
    __shared__ float r_eff_sh;
    const int t = threadIdx.x;
    red[t] = softplus_f(R[t]);
    __syncthreads();
    for (int s = 256; s > 0; s >>= 1) {
        if (t < s) red[t] += red[t + s];
        __syncthreads();
    }
    if (t == 0) r_eff_sh = red[0] / 512.0f;
    __syncthreads();
    const float r_eff = r_eff_sh;
    if (t < NS) {
        const float q = softplus_f(Q[t]);
        float P = 1.0f;
        for (int step = 0; step < NT; ++step) {
            float Pp = fminf(fmaxf(P + q, 1e-6f), 10.0f);
            float K  = fminf(fmaxf(Pp / (Pp + r_eff + 1e-6f), 0.0f), 1.0f);
            Kt[(size_t)step * NS + t] = K;
            P = fminf(fmaxf(Pp * (1.0f - K), 1e-6f), 10.0f);
        }
    }
}

__global__ void k_transpose(const float* __restrict__ in, float* __restrict__ outp,
                            int Rr, int Cc) {
    int i = blockIdx.x * 256 + threadIdx.x;
    if (i < Rr * Cc) {
        int r = i / Cc, c = i % Cc;
        outp[(size_t)c * Rr + r] = in[i];
    }
}

__global__ void k_ig(const float* __restrict__ G, const float* __restrict__ Kt,
                     float* __restrict__ IG) {
    int i = blockIdx.x * 256 + threadIdx.x;
    if (i >= NS * NS) return;
    int r = i >> 8, c = i & 255;
    float kinf = Kt[(size_t)(NT - 1) * NS + c];
    IG[i] = ((r == c) ? 1.0f : 0.0f) - G[i] * kinf;
}

__global__ void k_fuse(const float* __restrict__ us, const float* __restrict__ usG,
                       const float* __restrict__ Hu, const float* __restrict__ Kt,
                       float* __restrict__ u3) {
    int i = blockIdx.x * 256 + threadIdx.x;
    if (i >= NT * NB * NS) return;
    int s = i & 255;
    int tm = i >> 8;
    int m = tm & 15, t = tm >> 4;
    size_t src = ((size_t)m * NT + t) * NS + s;
    float k = Kt[(size_t)t * NS + s];
    u3[i] = us[src] + k * (Hu[src] - usG[src]);
}

// ---- Wg_cat [256][384] = [Wz_x | Wr_x | Wh_x] ; bg = [bz|br|bh] ----
__global__ void k_build(const float* __restrict__ Wzt, const float* __restrict__ Wrt,
                        const float* __restrict__ Wht,
                        const float* __restrict__ bz, const float* __restrict__ br,
                        const float* __restrict__ bh,
                        float* __restrict__ Wg, float* __restrict__ bg) {
    int i = blockIdx.x * 256 + threadIdx.x;
    if (i < 256 * 384) {
        int s = i / 384, j = i % 384;
        const float* src = (j < 128) ? Wzt : (j < 256) ? Wrt : Wht;
        int jj = j & 127;
        Wg[i] = src[(size_t)(128 + s) * 128 + jj];
    }
    if (i < 384) {
        bg[i] = (i < 128) ? bz[i] : (i < 256) ? br[i - 128] : bh[i - 256];
    }
}

// ---- pack W[K][N] f32 -> bf16 frags ----
__global__ void k_pack(const float* __restrict__ W, short* __restrict__ dst, int K, int N) {
    int f = blockIdx.x * 256 + threadIdx.x;
    if (f >= K * N) return;
    const int j = f & 7, l = (f >> 3) & 63, tile = f >> 9;
    const int KS = K >> 5;
    const int nt = tile / KS, ks = tile - nt * KS;
    const int k = ks * 32 + (l >> 4) * 8 + j;
    const int n = nt * 16 + (l & 15);
    dst[f] = f2bf_s(W[(size_t)k * N + n]);
}

// ---- bf16 MFMA GEMM with fused f32->bf16 A conversion ----
__global__ __launch_bounds__(256) void k_mm(const float* __restrict__ Af,
                                            const short* __restrict__ Bpk,
                                            const float* __restrict__ bias,
                                            const float* __restrict__ resid,
                                            float* __restrict__ C,
                                            int N, int K, int act) {
    const int tid = threadIdx.x, w = tid >> 6, l = tid & 63;
    const int KS = K >> 5;
    const int mt = blockIdx.x * 4 + w;
    const int nt0 = blockIdx.y * 8;
    const float* arow = Af + (size_t)(mt * 16 + (l & 15)) * K + ((l >> 4) * 8);
    f32x4 acc[8];
#pragma unroll
    for (int j = 0; j < 8; ++j) acc[j] = (f32x4){0.f, 0.f, 0.f, 0.f};
    for (int ks = 0; ks < KS; ++ks) {
        const float* ap = arow + ks * 32;
        f32x4 a0 = *(const f32x4*)ap;
        f32x4 a1 = *(const f32x4*)(ap + 4);
        union { bf16x8 v; unsigned u[4]; } au;
        au.u[0] = pk_bf(a0[0], a0[1]); au.u[1] = pk_bf(a0[2], a0[3]);
        au.u[2] = pk_bf(a1[0], a1[1]); au.u[3] = pk_bf(a1[2], a1[3]);
#pragma unroll
        for (int j = 0; j < 8; ++j) {
            bf16x8 b = *(const bf16x8*)(Bpk + ((size_t)(nt0 + j) * KS + ks) * 512 + (size_t)l * 8);
            acc[j] = MFMA(b, au.v, acc[j]);
        }
    }
    const int m = mt * 16 + (l & 15);
    const int lg = l >> 4;
#pragma unroll
    for (int j = 0; j < 8; ++j) {
        const int n = (nt0 + j) * 16 + lg * 4;
        f32x4 v = acc[j];
        if (bias) v += *(const f32x4*)(bias + n);
        if (act) {
#pragma unroll
            for (int r = 0; r < 4; ++r) v[r] = gelu_tanh(v[r]);
        }
        if (resid) v += *(const f32x4*)(resid + (size_t)m * N + n);
        *(f32x4*)(C + (size_t)m * N + n) = v;
    }
}

// ---- f32 tiled GEMM (small exact matrices) ----
__global__ __launch_bounds__(256) void k_gemm(const float* __restrict__ Am,
                                              const float* __restrict__ Bm,
                                              const float* __restrict__ bias,
                                              const float* __restrict__ resid,
                                              float* __restrict__ Cm,
                                              int M, int N, int K, int act) {
    __shared__ __align__(16) float As[16][68];
    __shared__ __align__(16) float Bs[16][68];
    const int tid = threadIdx.x;
    const int bn = blockIdx.x, bm = blockIdx.y;
    const int row0 = bm * 64, col0 = bn * 64;
    const int tx = tid & 15, ty = tid >> 4;
    const int ar = tid >> 2, ac = (tid & 3) << 2;
    const int bk = tid >> 4, bc = (tid & 15) << 2;

    float acc[4][4];
#pragma unroll
    for (int i = 0; i < 4; ++i)
#pragma unroll
        for (int j = 0; j < 4; ++j) acc[i][j] = 0.0f;

    for (int k0 = 0; k0 < K; k0 += 16) {
        float4 av = *(const float4*)(Am + (size_t)(row0 + ar) * K + k0 + ac);
        float4 bv = *(const float4*)(Bm + (size_t)(k0 + bk) * N + col0 + bc);
        As[ac + 0][ar] = av.x; As[ac + 1][ar] = av.y;
        As[ac + 2][ar] = av.z; As[ac + 3][ar] = av.w;
        *(float4*)&Bs[bk][bc] = bv;
        __syncthreads();
#pragma unroll
        for (int kk = 0; kk < 16; ++kk) {
            const float a0 = As[kk][ty * 4 + 0], a1 = As[kk][ty * 4 + 1];
            const float a2 = As[kk][ty * 4 + 2], a3 = As[kk][ty * 4 + 3];
            const float4 b4 = *(const float4*)&Bs[kk][tx * 4];
            acc[0][0] += a0 * b4.x; acc[0][1] += a0 * b4.y; acc[0][2] += a0 * b4.z; acc[0][3] += a0 * b4.w;
            acc[1][0] += a1 * b4.x; acc[1][1] += a1 * b4.y; acc[1][2] += a1 * b4.z; acc[1][3] += a1 * b4.w;
            acc[2][0] += a2 * b4.x; acc[2][1] += a2 * b4.y; acc[2][2] += a2 * b4.z; acc[2][3] += a2 * b4.w;
            acc[3][0] += a3 * b4.x; acc[3][1] += a3 * b4.y; acc[3][2] += a3 * b4.z; acc[3][3] += a3 * b4.w;
        }
        __syncthreads();
    }
#pragma unroll
    for (int i = 0; i < 4; ++i) {
        const int r = row0 + ty * 4 + i;
#pragma unroll
        for (int j = 0; j < 4; ++j) {
            const int c = col0 + tx * 4 + j;
            float v = acc[i][j];
            if (bias) v += bias[c];
            if (act) v = gelu_tanh(v);
            if (resid) v += resid[(size_t)r * N + c];
            Cm[(size_t)r * N + c] = v;
        }
    }
}

// ===================== MFMA scan: gate-linearized, 3 barriers/step =====================
#define XE_STR 528
#define HB_STR 272

__global__ __launch_bounds__(512, 2) void k_scan_mfma(
    const short* __restrict__ pM, const short* __restrict__ pA, const short* __restrict__ pG,
    const short* __restrict__ pZ, const short* __restrict__ pR, const short* __restrict__ pH,
    const short* __restrict__ pO, const short* __restrict__ pMG,
    const float* __restrict__ bz, const float* __restrict__ br, const float* __restrict__ bh,
    const float* __restrict__ us, const float* __restrict__ Hu,
    const float* __restrict__ u3, const float* __restrict__ ug,
    const float* __restrict__ Kt, float* __restrict__ xs)
{
    __shared__ __align__(16) char XE[16 * XE_STR];
    __shared__ __align__(16) char XT[16 * XE_STR];   // early phase only
    __shared__ __align__(16) char HBs[16 * HB_STR];
    __shared__ __align__(16) char RGs[16 * HB_STR];
    __shared__ __align__(16) char MHH[64 * 1024];    // MH' = Minf@Wh_x frags (8/wave)
    __shared__ __align__(16) char WH2[32 * 1024];    // Wh_h frags (4/wave)

    const int tid = threadIdx.x, w = tid >> 6, l = tid & 63;
    const int m = l & 15, lg = l >> 4;
    const int c0 = 32 * w + 4 * lg;
    const int cg = 16 * w + 4 * lg;

    for (int i = tid; i < (16 * XE_STR) / 4; i += 512) ((int*)XE)[i] = 0;
    for (int i = tid; i < (16 * HB_STR) / 4; i += 512) ((int*)HBs)[i] = 0;
    for (int i = tid; i < 4096; i += 512) {
        int fi = i >> 6, ln = i & 63;
        int wv = fi >> 3, ks = fi & 7;
        ((int4*)MHH)[i] = *(const int4*)(pMG + ((size_t)((16 + wv) * 8 + ks) * 64 + ln) * 8);
    }
    for (int i = tid; i < 2048; i += 512) {
        int fi = i >> 6, ln = i & 63;
        int nt = fi >> 2, ks = fi & 3;
        ((int4*)WH2)[i] = *(const int4*)(pH + ((size_t)(nt * 12 + ks) * 64 + ln) * 8);
    }

    const f32x4 bzv = *(const f32x4*)(bz + cg);
    const f32x4 brv = *(const f32x4*)(br + cg);
    const f32x4 bhv = *(const f32x4*)(bh + cg);
    f32x4 hFr = {0.f, 0.f, 0.f, 0.f};
    __syncthreads();

    // ------------- early phase t<T0 (exact per-t K, streamed weights) -------------
    for (int t = 0; t < T0; ++t) {
        const float* usb = us + ((size_t)m * NT + t) * NS;
        const float* hub = Hu + ((size_t)m * NT + t) * NS;
        const float* ktb = Kt + (size_t)t * NS;
        f32x4 us0 = *(const f32x4*)(usb + c0), us1 = *(const f32x4*)(usb + c0 + 16);
        f32x4 hu0 = *(const f32x4*)(hub + c0), hu1 = *(const f32x4*)(hub + c0 + 16);
        f32x4 kv0 = *(const f32x4*)(ktb + c0), kv1 = *(const f32x4*)(ktb + c0 + 16);
        f32x4 p0 = {0.f,0.f,0.f,0.f}, p1 = {0.f,0.f,0.f,0.f};
#pragma unroll
        for (int ks = 0; ks < 8; ++ks) {
            bf16x8 xe = BFRAG(XE, XE_STR, ks);
            p0 = MFMA(GFRAG(pA, (2 * w + 0) * 8 + ks), xe, p0);
            p1 = MFMA(GFRAG(pA, (2 * w + 1) * 8 + ks), xe, p1);
        }
        p0 += us0; p1 += us1;
        st_bf4(XT, XE_STR, m, c0 * 2, p0);
        st_bf4(XT, XE_STR, m, (c0 + 16) * 2, p1);
        SYNCW();
        f32x4 g0 = {0.f,0.f,0.f,0.f}, g1 = {0.f,0.f,0.f,0.f};
#pragma unroll
        for (int ks = 0; ks < 8; ++ks) {
            bf16x8 xt = BFRAG(XT, XE_STR, ks);
            g0 = MFMA(GFRAG(pG, (2 * w + 0) * 8 + ks), xt, g0);
            g1 = MFMA(GFRAG(pG, (2 * w + 1) * 8 + ks), xt, g1);
        }
        f32x4 xq0 = p0 + kv0 * (hu0 - g0);
        f32x4 xq1 = p1 + kv1 * (hu1 - g1);
        st_bf4(XE, XE_STR, m, c0 * 2, xq0);
        st_bf4(XE, XE_STR, m, (c0 + 16) * 2, xq1);
        SYNCW();
        f32x4 za = bzv, ra = brv, hx = bhv;
#pragma unroll
        for (int ks = 0; ks < 4; ++ks) {
            bf16x8 hb = BFRAG(HBs, HB_STR, ks);
            za = MFMA(GFRAG(pZ, w * 12 + ks), hb, za);
            ra = MFMA(GFRAG(pR, w * 12 + ks), hb, ra);
        }
#pragma unroll
        for (int ks = 0; ks < 8; ++ks) {
            bf16x8 xef = BFRAG(XE, XE_STR, ks);
            za = MFMA(GFRAG(pZ, w * 12 + 4 + ks), xef, za);
            ra = MFMA(GFRAG(pR, w * 12 + 4 + ks), xef, ra);
            hx = MFMA(GFRAG(pH, w * 12 + 4 + ks), xef, hx);
        }
        f32x4 z = sig4(za), r = sig4(ra), rg = r * hFr;
        st_bf4(RGs, HB_STR, m, cg * 2, rg);
        SYNCW();
        f32x4 hc = hx;
#pragma unroll
        for (int ks = 0; ks < 4; ++ks)
            hc = MFMA(GFRAG(pH, w * 12 + ks), BFRAG(RGs, HB_STR, ks), hc);
        f32x4 hcv = tanh4(hc);
        f32x4 hn = hFr + z * (hcv - hFr);
        hFr = hn;
        st_bf4(HBs, HB_STR, m, cg * 2, hn);
        SYNCW();
#pragma unroll
        for (int ks = 0; ks < 4; ++ks) {
            bf16x8 hb2 = BFRAG(HBs, HB_STR, ks);
            xq0 = MFMA(GFRAG(pO, (2 * w + 0) * 4 + ks), hb2, xq0);
            xq1 = MFMA(GFRAG(pO, (2 * w + 1) * 4 + ks), hb2, xq1);
        }
        st_bf4(XE, XE_STR, m, c0 * 2, xq0);
        st_bf4(XE, XE_STR, m, (c0 + 16) * 2, xq1);
        {
            float* xb = xs + ((size_t)m * NT + t) * NS;
            *(f32x4*)(xb + c0) = xq0;
            *(f32x4*)(xb + c0 + 16) = xq1;
        }
        SYNCW();
    }

    // ------------- register weights for main loop (192 regs, validated budget) -------------
    bf16x8 rM0[8], rM1[8], rMZ[8], rMR[8], rZh[4], rRh[4], rO0[4], rO1[4];
#pragma unroll
    for (int ks = 0; ks < 8; ++ks) {
        rM0[ks] = GFRAG(pM, (2 * w + 0) * 8 + ks);
        rM1[ks] = GFRAG(pM, (2 * w + 1) * 8 + ks);
        rMZ[ks] = GFRAG(pMG, w * 8 + ks);
        rMR[ks] = GFRAG(pMG, (8 + w) * 8 + ks);
    }
#pragma unroll
    for (int ks = 0; ks < 4; ++ks) {
        rZh[ks] = GFRAG(pZ, w * 12 + ks);
        rRh[ks] = GFRAG(pR, w * 12 + ks);
        rO0[ks] = GFRAG(pO, (2 * w + 0) * 4 + ks);
        rO1[ks] = GFRAG(pO, (2 * w + 1) * 4 + ks);
    }

    // initial h-gate carries (NO bias: bias arrives via ug)
    f32x4 zh = {0.f,0.f,0.f,0.f}, rh = {0.f,0.f,0.f,0.f};
#pragma unroll
    for (int ks = 0; ks < 4; ++ks) {
        bf16x8 hb = BFRAG(HBs, HB_STR, ks);
        zh = MFMA(rZh[ks], hb, zh);
        rh = MFMA(rRh[ks], hb, rh);
    }

    // ------------- main loop: 3 barriers/step -------------
    for (int t = T0; t < NT; ++t) {
        const float* ubase = u3 + ((size_t)(t * NB) + m) * NS;
        const float* gbase = ug + ((size_t)(t * NB) + m) * 384;
        f32x4 cu0 = *(const f32x4*)(ubase + c0);
        f32x4 cu1 = *(const f32x4*)(ubase + c0 + 16);
        f32x4 cz  = *(const f32x4*)(gbase + cg);
        f32x4 cr  = *(const f32x4*)(gbase + 128 + cg);
        f32x4 chx = *(const f32x4*)(gbase + 256 + cg);

        // ph1: x_post + both gates + hc-x-part, all off {x_est, carries}
        f32x4 xq0 = {0.f,0.f,0.f,0.f}, xq1 = {0.f,0.f,0.f,0.f};
        f32x4 za = zh, ra = rh, hx = {0.f,0.f,0.f,0.f};
#pragma unroll
        for (int ks = 0; ks < 8; ++ks) {
            bf16x8 xe = BFRAG(XE, XE_STR, ks);
            bf16x8 mh = LFRAG(MHH, w * 8 + ks);
            xq0 = MFMA(rM0[ks], xe, xq0);
            xq1 = MFMA(rM1[ks], xe, xq1);
            za  = MFMA(rMZ[ks], xe, za);
            ra  = MFMA(rMR[ks], xe, ra);
            hx  = MFMA(mh,      xe, hx);
        }
        xq0 += cu0; xq1 += cu1; za += cz; ra += cr;
        f32x4 z = sig4(za), r = sig4(ra), rg = r * hFr;
        st_bf4(RGs, HB_STR, m, cg * 2, rg);
        SYNCW();  // bar A
        // ph2a: hc, h update
        f32x4 hc = hx + chx;
#pragma unroll
        for (int ks = 0; ks < 4; ++ks)
            hc = MFMA(LFRAG(WH2, w * 4 + ks), BFRAG(RGs, HB_STR, ks), hc);
        f32x4 hcv = tanh4(hc);
        f32x4 hn = hFr + z * (hcv - hFr);
        hFr = hn;
        st_bf4(HBs, HB_STR, m, cg * 2, hn);
        SYNCW();  // bar B
        // ph2b: x_final = x_post + h@Wout ; next-step h-gate carries
        f32x4 zhN = {0.f,0.f,0.f,0.f}, rhN = {0.f,0.f,0.f,0.f};
#pragma unroll
        for (int ks = 0; ks < 4; ++ks) {
            bf16x8 hb2 = BFRAG(HBs, HB_STR, ks);
            xq0 = MFMA(rO0[ks], hb2, xq0);
            xq1 = MFMA(rO1[ks], hb2, xq1);
            zhN = MFMA(rZh[ks], hb2, zhN);
            rhN = MFMA(rRh[ks], hb2, rhN);
        }
        st_bf4(XE, XE_STR, m, c0 * 2, xq0);
        st_bf4(XE, XE_STR, m, (c0 + 16) * 2, xq1);
        {
            float* xb = xs + ((size_t)m * NT + t) * NS;
            *(f32x4*)(xb + c0) = xq0;
            *(f32x4*)(xb + c0 + 16) = xq1;
        }
        zh = zhN; rh = rhN;
        SYNCW();  // bar C
    }
}

extern "C" void kernel_launch(void* const* d_in, const int* in_sizes, int n_in,
                              void* d_out, int out_size, void* d_ws, size_t ws_size,
                              hipStream_t stream) {
    (void)in_sizes; (void)n_in; (void)out_size; (void)ws_size;
    const float* x       = (const float*)d_in[0];
    const float* W_in    = (const float*)d_in[1];
    const float* b_in    = (const float*)d_in[2];
    const float* W_state = (const float*)d_in[3];
    const float* b_state = (const float*)d_in[4];
    const float* A       = (const float*)d_in[5];
    const float* H       = (const float*)d_in[6];
    const float* Q       = (const float*)d_in[7];
    const float* R       = (const float*)d_in[8];
    const float* W_z     = (const float*)d_in[9];
    const float* W_r     = (const float*)d_in[10];
    const float* W_h     = (const float*)d_in[11];
    const float* b_z     = (const float*)d_in[12];
    const float* b_r     = (const float*)d_in[13];
    const float* b_h     = (const float*)d_in[14];
    const float* W_out   = (const float*)d_in[15];
    const float* W_outp  = (const float*)d_in[16];
    const float* b_outp  = (const float*)d_in[17];
    float* out = (float*)d_out;
    float* w = (float*)d_ws;

    float* us   = w + OFF_US;
    float* Hu   = w + OFF_HU;
    float* u3   = w + OFF_U3;
    float* Kt   = w + OFF_KT;
    float* Ht   = w + OFF_HT;
    float* At   = w + OFF_AT;
    float* G    = w + OFF_G;
    float* IG   = w + OFF_IG;
    float* Minf = w + OFF_MINF;
    float* Wzt  = w + OFF_WZT;
    float* Wrt  = w + OFF_WRT;
    float* Wht  = w + OFF_WHT;
    float* HtWo = w + OFF_HTWO;
    float* Wg   = w + OFF_WG;
    float* bg   = w + OFF_BG;
    float* Mg   = w + OFF_MG;
    short* pk   = (short*)(w + OFF_PACK);

    float* xs  = w + OFF_US;                 // aliases us: read-before-write per step
    float* ug  = out;                        // d_out [0..6.29M) (after usG dead)
    float* usG = out + (size_t)4194304;      // d_out [4.19M..8.39M)
    float* u   = out + (size_t)8388608;      // d_out upper half

    const int M = NB * NT;  // 16384

    hipLaunchKernelGGL(k_precompute, dim3(1), dim3(512), 0, stream, Q, R, Kt);
    hipLaunchKernelGGL(k_transpose, dim3((NS * NS + 255) / 256), dim3(256), 0, stream, A, At, NS, NS);
    hipLaunchKernelGGL(k_transpose, dim3((ND * NS + 255) / 256), dim3(256), 0, stream, H, Ht, ND, NS);
    hipLaunchKernelGGL(k_transpose, dim3((NH * 384 + 255) / 256), dim3(256), 0, stream, W_z, Wzt, NH, 384);
    hipLaunchKernelGGL(k_transpose, dim3((NH * 384 + 255) / 256), dim3(256), 0, stream, W_r, Wrt, NH, 384);
    hipLaunchKernelGGL(k_transpose, dim3((NH * 384 + 255) / 256), dim3(256), 0, stream, W_h, Wht, NH, 384);
    // exact f32 small GEMMs
    hipLaunchKernelGGL(k_gemm, dim3(NS / 64, NS / 64), dim3(256), 0, stream,
                       Ht, H, nullptr, nullptr, G, NS, NS, ND, 0);
    hipLaunchKernelGGL(k_gemm, dim3(NE / 64, NS / 64), dim3(256), 0, stream,
                       Ht, W_outp, nullptr, nullptr, HtWo, NS, NE, ND, 0);
    hipLaunchKernelGGL(k_ig, dim3(256), dim3(256), 0, stream, G, Kt, IG);
    hipLaunchKernelGGL(k_gemm, dim3(NS / 64, NS / 64), dim3(256), 0, stream,
                       At, IG, nullptr, nullptr, Minf, NS, NS, NS, 0);
    // gate-linearization matrices
    hipLaunchKernelGGL(k_build, dim3(384), dim3(256), 0, stream,
                       Wzt, Wrt, Wht, b_z, b_r, b_h, Wg, bg);
    hipLaunchKernelGGL(k_gemm, dim3(384 / 64, NS / 64), dim3(256), 0, stream,
                       Minf, Wg, nullptr, nullptr, Mg, NS, 384, NS, 0);
    // weight packs
    hipLaunchKernelGGL(k_pack, dim3((NS * NS + 255) / 256), dim3(256), 0, stream, At, pk + PK_A, NS, NS);
    hipLaunchKernelGGL(k_pack, dim3((NS * NS + 255) / 256), dim3(256), 0, stream, G, pk + PK_G, NS, NS);
    hipLaunchKernelGGL(k_pack, dim3((NS * NS + 255) / 256), dim3(256), 0, stream, Minf, pk + PK_M, NS, NS);
    hipLaunchKernelGGL(k_pack, dim3((384 * NH + 255) / 256), dim3(256), 0, stream, Wzt, pk + PK_Z, 384, NH);
    hipLaunchKernelGGL(k_pack, dim3((384 * NH + 255) / 256), dim3(256), 0, stream, Wrt, pk + PK_R, 384, NH);
    hipLaunchKernelGGL(k_pack, dim3((384 * NH + 255) / 256), dim3(256), 0, stream, Wht, pk + PK_H, 384, NH);
    hipLaunchKernelGGL(k_pack, dim3((NH * NS + 255) / 256), dim3(256), 0, stream, W_out, pk + PK_O, NH, NS);
    hipLaunchKernelGGL(k_pack, dim3((NE * ND + 255) / 256), dim3(256), 0, stream, W_in, pk + PK_WIN, NE, ND);
    hipLaunchKernelGGL(k_pack, dim3((ND * NS + 255) / 256), dim3(256), 0, stream, W_state, pk + PK_WST, ND, NS);
    hipLaunchKernelGGL(k_pack, dim3((ND * NS + 255) / 256), dim3(256), 0, stream, H, pk + PK_HM, ND, NS);
    hipLaunchKernelGGL(k_pack, dim3((NS * NE + 255) / 256), dim3(256), 0, stream, HtWo, pk + PK_HTW, NS, NE);
    hipLaunchKernelGGL(k_pack, dim3((NS * 384 + 255) / 256), dim3(256), 0, stream, Mg, pk + PK_MG, NS, 384);
    hipLaunchKernelGGL(k_pack, dim3((NS * 384 + 255) / 256), dim3(256), 0, stream, Wg, pk + PK_WG, NS, 384);
    // u = gelu(x@W_in + b_in)
    hipLaunchKernelGGL(k_mm, dim3(M / 64, ND / 128), dim3(256), 0, stream,
                       x, pk + PK_WIN, b_in, nullptr, u, ND, NE, 1);
    // us, Hu
    hipLaunchKernelGGL(k_mm, dim3(M / 64, NS / 128), dim3(256), 0, stream,
                       u, pk + PK_WST, b_state, nullptr, us, NS, ND, 0);
    hipLaunchKernelGGL(k_mm, dim3(M / 64, NS / 128), dim3(256), 0, stream,
                       u, pk + PK_HM, nullptr, nullptr, Hu, NS, ND, 0);
    // usG = us@G ; u3 = us + K.*(Hu - usG)
    hipLaunchKernelGGL(k_mm, dim3(M / 64, NS / 128), dim3(256), 0, stream,
                       us, pk + PK_G, nullptr, nullptr, usG, NS, NS, 0);
    hipLaunchKernelGGL(k_fuse, dim3((NT * NB * NS) / 256), dim3(256), 0, stream,
                       us, usG, Hu, Kt, u3);
    // ug = u3@Wg + bg  (usG dead; writes d_out[0..6.29M))
    hipLaunchKernelGGL(k_mm, dim3(M / 64, 384 / 128), dim3(256), 0, stream,
                       u3, pk + PK_WG, bg, nullptr, ug, 384, NS, 0);
    // scan (xs overwrites us in place)
    hipLaunchKernelGGL(k_scan_mfma, dim3(1), dim3(512), 0, stream,
                       pk + PK_M, pk + PK_A, pk + PK_G, pk + PK_Z, pk + PK_R, pk + PK_H,
                       pk + PK_O, pk + PK_MG,
                       b_z, b_r, b_h, us, Hu, u3, ug, Kt, xs);
    // out = xs@(Ht@W_outp) + b_outp + x
    hipLaunchKernelGGL(k_mm, dim3(M / 64, NE / 128), dim3(256), 0, stream,
                       xs, pk + PK_HTW, b_outp, x, out, NE, NS, 0);
}

// Round 13
// 3536.287 us; speedup vs baseline: 1.4575x; 1.4575x over previous
//
#include <hip/hip_runtime.h>
#include <cstdint>
#include <cstddef>

// Problem dims
#define NB 16
#define NT 1024
#define NE 1024
#define NS 256
#define ND 512
#define NH 128
#define T0 16

// ---- ws layout (float offsets) ----
#define OFF_US   ((size_t)0)          // us [m][t][s]; scan overwrites in-place as xs
#define OFF_HU   ((size_t)4194304)
#define OFF_U3   ((size_t)8388608)
#define OFF_KT   ((size_t)12582912)
#define OFF_HT   ((size_t)12845056)
#define OFF_AT   ((size_t)12976128)
#define OFF_G    ((size_t)13041664)
#define OFF_IG   ((size_t)13107200)
#define OFF_MINF ((size_t)13172736)
#define OFF_WZT  ((size_t)13238272)
#define OFF_WRT  ((size_t)13287424)
#define OFF_WHT  ((size_t)13336576)
#define OFF_HTWO ((size_t)13385728)   // 256*1024
#define OFF_PACK ((size_t)13647872)   // 1425408 shorts -> ws end 14360576 fl (57.4MB)

// pack sub-offsets (shorts)
#define PK_A   0
#define PK_G   65536
#define PK_M   131072
#define PK_Z   196608
#define PK_R   245760
#define PK_H   294912
#define PK_O   344064
#define PK_WIN 376832
#define PK_WST 901120
#define PK_HM  1032192
#define PK_HTW 1163264

// d_out scratch (floats): usG [4.19M..8.39M); u f32 [8.39M..16.78M) (dead after us/Hu).
// Final GEMM reads xs from ws and overwrites all of d_out — disjoint.

typedef short bf16x8 __attribute__((ext_vector_type(8)));
typedef float f32x4 __attribute__((ext_vector_type(4)));
typedef unsigned int u32x2 __attribute__((ext_vector_type(2)));

#define MFMA(a, b, c) __builtin_amdgcn_mfma_f32_16x16x32_bf16((a), (b), (c), 0, 0, 0)

// barrier WITHOUT vmcnt drain
#define SYNCW() do { \
    __builtin_amdgcn_sched_barrier(0); \
    asm volatile("s_waitcnt lgkmcnt(0)" ::: "memory"); \
    __builtin_amdgcn_s_barrier(); \
    __builtin_amdgcn_sched_barrier(0); \
} while (0)

__device__ __forceinline__ float gelu_tanh(float v) {
    const float c = 0.7978845608028654f;
    float t = tanhf(c * (v + 0.044715f * v * v * v));
    return 0.5f * v * (1.0f + t);
}
__device__ __forceinline__ float softplus_f(float x) {
    if (x > 20.0f) return x;
    return log1pf(expf(x));
}
__device__ __forceinline__ short f2bf_s(float f) {
    unsigned u = __float_as_uint(f);
    u += 0x7fffu + ((u >> 16) & 1u);
    return (short)(u >> 16);
}
__device__ __forceinline__ unsigned pk_bf(float a, float b) {
    return ((unsigned)(unsigned short)f2bf_s(b) << 16) | (unsigned)(unsigned short)f2bf_s(a);
}
__device__ __forceinline__ float exp2_hw(float x) {
    float r; asm("v_exp_f32 %0, %1" : "=v"(r) : "v"(x)); return r;
}
__device__ __forceinline__ float rcp_hw(float x) {
    float r; asm("v_rcp_f32 %0, %1" : "=v"(r) : "v"(x)); return r;
}
__device__ __forceinline__ f32x4 sig4(f32x4 x) {
    f32x4 o;
#pragma unroll
    for (int i = 0; i < 4; ++i)
        o[i] = rcp_hw(1.0f + exp2_hw(-1.442695040888963f * x[i]));
    return o;
}
__device__ __forceinline__ f32x4 tanh4(f32x4 x) {
    f32x4 o;
#pragma unroll
    for (int i = 0; i < 4; ++i) {
        float e = exp2_hw(2.885390081777927f * x[i]);
        o[i] = 1.0f - 2.0f * rcp_hw(e + 1.0f);
    }
    return o;
}
__device__ __forceinline__ void st_bf4(char* base, int stride, int row, int byteoff,
                                       const f32x4& v) {
    u32x2 p;
    p[0] = pk_bf(v[0], v[1]);
    p[1] = pk_bf(v[2], v[3]);
    *(u32x2*)(base + row * stride + byteoff) = p;
}

#define BFRAG(buf, STR, ks) (*(const bf16x8*)((buf) + (l & 15) * (STR) + (ks) * 64 + (l >> 4) * 16))
#define GFRAG(p, fi) (*(const bf16x8*)((p) + ((size_t)(fi) * 64 + l) * 8))
#define LFRAG(buf, fi) (*(const bf16x8*)((buf) + (size_t)(fi) * 1024 + l * 16))

// ---- P/K covariance recurrence ----
__global__ __launch_bounds__(512) void k_precompute(const float* __restrict__ Q,
                                                    const float* __restrict__ R,
                                                    float* __restrict__ Kt) {
    __shared__ float red[512];
    __shared__ float r_eff_sh;
    const int t = threadIdx.x;
    red[t] = softplus_f(R[t]);
    __syncthreads();
    for (int s = 256; s > 0; s >>= 1) {
        if (t < s) red[t] += red[t + s];
        __syncthreads();
    }
    if (t == 0) r_eff_sh = red[0] / 512.0f;
    __syncthreads();
    const float r_eff = r_eff_sh;
    if (t < NS) {
        const float q = softplus_f(Q[t]);
        float P = 1.0f;
        for (int step = 0; step < NT; ++step) {
            float Pp = fminf(fmaxf(P + q, 1e-6f), 10.0f);
            float K  = fminf(fmaxf(Pp / (Pp + r_eff + 1e-6f), 0.0f), 1.0f);
            Kt[(size_t)step * NS + t] = K;
            P = fminf(fmaxf(Pp * (1.0f - K), 1e-6f), 10.0f);
        }
    }
}

__global__ void k_transpose(const float* __restrict__ in, float* __restrict__ outp,
                            int Rr, int Cc) {
    int i = blockIdx.x * 256 + threadIdx.x;
    if (i < Rr * Cc) {
        int r = i / Cc, c = i % Cc;
        outp[(size_t)c * Rr + r] = in[i];
    }
}

__global__ void k_ig(const float* __restrict__ G, const float* __restrict__ Kt,
                     float* __restrict__ IG) {
    int i = blockIdx.x * 256 + threadIdx.x;
    if (i >= NS * NS) return;
    int r = i >> 8, c = i & 255;
    float kinf = Kt[(size_t)(NT - 1) * NS + c];
    IG[i] = ((r == c) ? 1.0f : 0.0f) - G[i] * kinf;
}

__global__ void k_fuse(const float* __restrict__ us, const float* __restrict__ usG,
                       const float* __restrict__ Hu, const float* __restrict__ Kt,
                       float* __restrict__ u3) {
    int i = blockIdx.x * 256 + threadIdx.x;
    if (i >= NT * NB * NS) return;
    int s = i & 255;
    int tm = i >> 8;
    int m = tm & 15, t = tm >> 4;
    size_t src = ((size_t)m * NT + t) * NS + s;
    float k = Kt[(size_t)t * NS + s];
    u3[i] = us[src] + k * (Hu[src] - usG[src]);
}

// ---- pack W[K][N] f32 -> bf16 B-operand frags ----
__global__ void k_pack(const float* __restrict__ W, short* __restrict__ dst, int K, int N) {
    int f = blockIdx.x * 256 + threadIdx.x;
    if (f >= K * N) return;
    const int j = f & 7, l = (f >> 3) & 63, tile = f >> 9;
    const int KS = K >> 5;
    const int nt = tile / KS, ks = tile - nt * KS;
    const int k = ks * 32 + (l >> 4) * 8 + j;
    const int n = nt * 16 + (l & 15);
    dst[f] = f2bf_s(W[(size_t)k * N + n]);
}

// ---- bf16 MFMA GEMM with fused f32->bf16 A conversion ----
__global__ __launch_bounds__(256) void k_mm(const float* __restrict__ Af,
                                            const short* __restrict__ Bpk,
                                            const float* __restrict__ bias,
                                            const float* __restrict__ resid,
                                            float* __restrict__ C,
                                            int N, int K, int act) {
    const int tid = threadIdx.x, w = tid >> 6, l = tid & 63;
    const int KS = K >> 5;
    const int mt = blockIdx.x * 4 + w;
    const int nt0 = blockIdx.y * 8;
    const float* arow = Af + (size_t)(mt * 16 + (l & 15)) * K + ((l >> 4) * 8);
    f32x4 acc[8];
#pragma unroll
    for (int j = 0; j < 8; ++j) acc[j] = (f32x4){0.f, 0.f, 0.f, 0.f};
    for (int ks = 0; ks < KS; ++ks) {
        const float* ap = arow + ks * 32;
        f32x4 a0 = *(const f32x4*)ap;
        f32x4 a1 = *(const f32x4*)(ap + 4);
        union { bf16x8 v; unsigned u[4]; } au;
        au.u[0] = pk_bf(a0[0], a0[1]); au.u[1] = pk_bf(a0[2], a0[3]);
        au.u[2] = pk_bf(a1[0], a1[1]); au.u[3] = pk_bf(a1[2], a1[3]);
#pragma unroll
        for (int j = 0; j < 8; ++j) {
            bf16x8 b = *(const bf16x8*)(Bpk + ((size_t)(nt0 + j) * KS + ks) * 512 + (size_t)l * 8);
            acc[j] = MFMA(b, au.v, acc[j]);
        }
    }
    const int m = mt * 16 + (l & 15);
    const int lg = l >> 4;
#pragma unroll
    for (int j = 0; j < 8; ++j) {
        const int n = (nt0 + j) * 16 + lg * 4;
        f32x4 v = acc[j];
        if (bias) v += *(const f32x4*)(bias + n);
        if (act) {
#pragma unroll
            for (int r = 0; r < 4; ++r) v[r] = gelu_tanh(v[r]);
        }
        if (resid) v += *(const f32x4*)(resid + (size_t)m * N + n);
        *(f32x4*)(C + (size_t)m * N + n) = v;
    }
}

// ---- f32 tiled GEMM (small exact matrices) ----
__global__ __launch_bounds__(256) void k_gemm(const float* __restrict__ Am,
                                              const float* __restrict__ Bm,
                                              const float* __restrict__ bias,
                                              const float* __restrict__ resid,
                                              float* __restrict__ Cm,
                                              int M, int N, int K, int act) {
    __shared__ __align__(16) float As[16][68];
    __shared__ __align__(16) float Bs[16][68];
    const int tid = threadIdx.x;
    const int bn = blockIdx.x, bm = blockIdx.y;
    const int row0 = bm * 64, col0 = bn * 64;
    const int tx = tid & 15, ty = tid >> 4;
    const int ar = tid >> 2, ac = (tid & 3) << 2;
    const int bk = tid >> 4, bc = (tid & 15) << 2;

    float acc[4][4];
#pragma unroll
    for (int i = 0; i < 4; ++i)
#pragma unroll
        for (int j = 0; j < 4; ++j) acc[i][j] = 0.0f;

    for (int k0 = 0; k0 < K; k0 += 16) {
        float4 av = *(const float4*)(Am + (size_t)(row0 + ar) * K + k0 + ac);
        float4 bv = *(const float4*)(Bm + (size_t)(k0 + bk) * N + col0 + bc);
        As[ac + 0][ar] = av.x; As[ac + 1][ar] = av.y;
        As[ac + 2][ar] = av.z; As[ac + 3][ar] = av.w;
        *(float4*)&Bs[bk][bc] = bv;
        __syncthreads();
#pragma unroll
        for (int kk = 0; kk < 16; ++kk) {
            const float a0 = As[kk][ty * 4 + 0], a1 = As[kk][ty * 4 + 1];
            const float a2 = As[kk][ty * 4 + 2], a3 = As[kk][ty * 4 + 3];
            const float4 b4 = *(const float4*)&Bs[kk][tx * 4];
            acc[0][0] += a0 * b4.x; acc[0][1] += a0 * b4.y; acc[0][2] += a0 * b4.z; acc[0][3] += a0 * b4.w;
            acc[1][0] += a1 * b4.x; acc[1][1] += a1 * b4.y; acc[1][2] += a1 * b4.z; acc[1][3] += a1 * b4.w;
            acc[2][0] += a2 * b4.x; acc[2][1] += a2 * b4.y; acc[2][2] += a2 * b4.z; acc[2][3] += a2 * b4.w;
            acc[3][0] += a3 * b4.x; acc[3][1] += a3 * b4.y; acc[3][2] += a3 * b4.z; acc[3][3] += a3 * b4.w;
        }
        __syncthreads();
    }
#pragma unroll
    for (int i = 0; i < 4; ++i) {
        const int r = row0 + ty * 4 + i;
#pragma unroll
        for (int j = 0; j < 4; ++j) {
            const int c = col0 + tx * 4 + j;
            float v = acc[i][j];
            if (bias) v += bias[c];
            if (act) v = gelu_tanh(v);
            if (resid) v += resid[(size_t)r * N + c];
            Cm[(size_t)r * N + c] = v;
        }
    }
}

// ===================== MFMA scan (round-9 structure + u3 prefetch) =====================
#define XE_STR 528
#define HB_STR 272

__global__ __launch_bounds__(512, 2) void k_scan_mfma(
    const short* __restrict__ pM, const short* __restrict__ pA, const short* __restrict__ pG,
    const short* __restrict__ pZ, const short* __restrict__ pR, const short* __restrict__ pH,
    const short* __restrict__ pO,
    const float* __restrict__ bz, const float* __restrict__ br, const float* __restrict__ bh,
    const float* __restrict__ us, const float* __restrict__ Hu, const float* __restrict__ u3,
    const float* __restrict__ Kt, float* __restrict__ xs)
{
    __shared__ __align__(16) char XE[16 * XE_STR];
    __shared__ __align__(16) char XT[16 * XE_STR];
    __shared__ __align__(16) char HBs[16 * HB_STR];
    __shared__ __align__(16) char RGs[16 * HB_STR];
    __shared__ __align__(16) char WHH[96 * 1024];

    const int tid = threadIdx.x, w = tid >> 6, l = tid & 63;
    const int m = l & 15, lg = l >> 4;
    const int c0 = 32 * w + 4 * lg;
    const int cg = 16 * w + 4 * lg;

    for (int i = tid; i < (16 * XE_STR) / 4; i += 512) ((int*)XE)[i] = 0;
    for (int i = tid; i < (16 * HB_STR) / 4; i += 512) ((int*)HBs)[i] = 0;
    for (int i = tid; i < 6144; i += 512) ((int4*)WHH)[i] = ((const int4*)pH)[i];

    const f32x4 bzv = *(const f32x4*)(bz + cg);
    const f32x4 brv = *(const f32x4*)(br + cg);
    const f32x4 bhv = *(const f32x4*)(bh + cg);
    f32x4 hFr = {0.f, 0.f, 0.f, 0.f};
    __syncthreads();

    // ------------- early phase t<T0 (exact per-t K, streamed weights) -------------
    for (int t = 0; t < T0; ++t) {
        const float* usb = us + ((size_t)m * NT + t) * NS;
        const float* hub = Hu + ((size_t)m * NT + t) * NS;
        const float* ktb = Kt + (size_t)t * NS;
        f32x4 us0 = *(const f32x4*)(usb + c0), us1 = *(const f32x4*)(usb + c0 + 16);
        f32x4 hu0 = *(const f32x4*)(hub + c0), hu1 = *(const f32x4*)(hub + c0 + 16);
        f32x4 kv0 = *(const f32x4*)(ktb + c0), kv1 = *(const f32x4*)(ktb + c0 + 16);
        f32x4 p0 = {0.f,0.f,0.f,0.f}, p1 = {0.f,0.f,0.f,0.f};
#pragma unroll
        for (int ks = 0; ks < 8; ++ks) {
            bf16x8 xe = BFRAG(XE, XE_STR, ks);
            p0 = MFMA(GFRAG(pA, (2 * w + 0) * 8 + ks), xe, p0);
            p1 = MFMA(GFRAG(pA, (2 * w + 1) * 8 + ks), xe, p1);
        }
        p0 += us0; p1 += us1;
        st_bf4(XT, XE_STR, m, c0 * 2, p0);
        st_bf4(XT, XE_STR, m, (c0 + 16) * 2, p1);
        SYNCW();
        f32x4 g0 = {0.f,0.f,0.f,0.f}, g1 = {0.f,0.f,0.f,0.f};
#pragma unroll
        for (int ks = 0; ks < 8; ++ks) {
            bf16x8 xt = BFRAG(XT, XE_STR, ks);
            g0 = MFMA(GFRAG(pG, (2 * w + 0) * 8 + ks), xt, g0);
            g1 = MFMA(GFRAG(pG, (2 * w + 1) * 8 + ks), xt, g1);
        }
        f32x4 xq0 = p0 + kv0 * (hu0 - g0);
        f32x4 xq1 = p1 + kv1 * (hu1 - g1);
        st_bf4(XE, XE_STR, m, c0 * 2, xq0);
        st_bf4(XE, XE_STR, m, (c0 + 16) * 2, xq1);
        SYNCW();
        f32x4 za = bzv, ra = brv, hx = bhv;
#pragma unroll
        for (int ks = 0; ks < 4; ++ks) {
            bf16x8 hb = BFRAG(HBs, HB_STR, ks);
            za = MFMA(GFRAG(pZ, w * 12 + ks), hb, za);
            ra = MFMA(GFRAG(pR, w * 12 + ks), hb, ra);
        }
#pragma unroll
        for (int ks = 0; ks < 8; ++ks) {
            bf16x8 xef = BFRAG(XE, XE_STR, ks);
            za = MFMA(GFRAG(pZ, w * 12 + 4 + ks), xef, za);
            ra = MFMA(GFRAG(pR, w * 12 + 4 + ks), xef, ra);
            hx = MFMA(GFRAG(pH, w * 12 + 4 + ks), xef, hx);
        }
        f32x4 z = sig4(za), r = sig4(ra), rg = r * hFr;
        st_bf4(RGs, HB_STR, m, cg * 2, rg);
        SYNCW();
        f32x4 hc = hx;
#pragma unroll
        for (int ks = 0; ks < 4; ++ks)
            hc = MFMA(GFRAG(pH, w * 12 + ks), BFRAG(RGs, HB_STR, ks), hc);
        f32x4 hcv = tanh4(hc);
        f32x4 hn = hFr + z * (hcv - hFr);
        hFr = hn;
        st_bf4(HBs, HB_STR, m, cg * 2, hn);
        SYNCW();
#pragma unroll
        for (int ks = 0; ks < 4; ++ks) {
            bf16x8 hb2 = BFRAG(HBs, HB_STR, ks);
            xq0 = MFMA(GFRAG(pO, (2 * w + 0) * 4 + ks), hb2, xq0);
            xq1 = MFMA(GFRAG(pO, (2 * w + 1) * 4 + ks), hb2, xq1);
        }
        st_bf4(XE, XE_STR, m, c0 * 2, xq0);
        st_bf4(XE, XE_STR, m, (c0 + 16) * 2, xq1);
        {
            float* xb = xs + ((size_t)m * NT + t) * NS;
            *(f32x4*)(xb + c0) = xq0;
            *(f32x4*)(xb + c0 + 16) = xq1;
        }
        SYNCW();
    }

    // ------------- register weights for main loop (192 static, validated) -------------
    bf16x8 rM0[8], rM1[8], rZx[8], rRx[8], rZh[4], rRh[4], rO0[4], rO1[4];
#pragma unroll
    for (int ks = 0; ks < 8; ++ks) {
        rM0[ks] = GFRAG(pM, (2 * w + 0) * 8 + ks);
        rM1[ks] = GFRAG(pM, (2 * w + 1) * 8 + ks);
        rZx[ks] = GFRAG(pZ, w * 12 + 4 + ks);
        rRx[ks] = GFRAG(pR, w * 12 + 4 + ks);
    }
#pragma unroll
    for (int ks = 0; ks < 4; ++ks) {
        rZh[ks] = GFRAG(pZ, w * 12 + ks);
        rRh[ks] = GFRAG(pR, w * 12 + ks);
        rO0[ks] = GFRAG(pO, (2 * w + 0) * 4 + ks);
        rO1[ks] = GFRAG(pO, (2 * w + 1) * 4 + ks);
    }

    f32x4 zh = bzv, rh = brv;
#pragma unroll
    for (int ks = 0; ks < 4; ++ks) {
        bf16x8 hb = BFRAG(HBs, HB_STR, ks);
        zh = MFMA(rZh[ks], hb, zh);
        rh = MFMA(rRh[ks], hb, rh);
    }

    // u3 prefetch prologue (+8 regs — the only scan change vs round 9)
    f32x4 cu0 = *(const f32x4*)(u3 + (size_t)T0 * (NB * NS) + (size_t)m * NS + c0);
    f32x4 cu1 = *(const f32x4*)(u3 + (size_t)T0 * (NB * NS) + (size_t)m * NS + c0 + 16);

    // ------------- main loop: 4 barriers/step -------------
    for (int t = T0; t < NT; ++t) {
        const int tn = (t + 1 < NT) ? (t + 1) : t;
        const float* ubn = u3 + (size_t)tn * (NB * NS) + (size_t)m * NS;
        f32x4 nx0 = *(const f32x4*)(ubn + c0);
        f32x4 nx1 = *(const f32x4*)(ubn + c0 + 16);

        f32x4 xq0 = {0.f,0.f,0.f,0.f}, xq1 = {0.f,0.f,0.f,0.f};
#pragma unroll
        for (int ks = 0; ks < 8; ++ks) {
            bf16x8 xe = BFRAG(XE, XE_STR, ks);
            xq0 = MFMA(rM0[ks], xe, xq0);
            xq1 = MFMA(rM1[ks], xe, xq1);
        }
        xq0 += cu0; xq1 += cu1;
        st_bf4(XT, XE_STR, m, c0 * 2, xq0);
        st_bf4(XT, XE_STR, m, (c0 + 16) * 2, xq1);
        SYNCW();  // bar A
        f32x4 za = zh, ra = rh, hx = bhv;
#pragma unroll
        for (int ks = 0; ks < 8; ++ks) {
            bf16x8 xt = BFRAG(XT, XE_STR, ks);
            za = MFMA(rZx[ks], xt, za);
            ra = MFMA(rRx[ks], xt, ra);
            hx = MFMA(LFRAG(WHH, w * 12 + 4 + ks), xt, hx);
        }
        f32x4 z = sig4(za), r = sig4(ra), rg = r * hFr;
        st_bf4(RGs, HB_STR, m, cg * 2, rg);
        SYNCW();  // bar B
        f32x4 hc = hx;
#pragma unroll
        for (int ks = 0; ks < 4; ++ks)
            hc = MFMA(LFRAG(WHH, w * 12 + ks), BFRAG(RGs, HB_STR, ks), hc);
        f32x4 hcv = tanh4(hc);
        f32x4 hn = hFr + z * (hcv - hFr);
        hFr = hn;
        st_bf4(HBs, HB_STR, m, cg * 2, hn);
        SYNCW();  // bar C
        f32x4 zhN = bzv, rhN = brv;
#pragma unroll
        for (int ks = 0; ks < 4; ++ks) {
            bf16x8 hb2 = BFRAG(HBs, HB_STR, ks);
            xq0 = MFMA(rO0[ks], hb2, xq0);
            xq1 = MFMA(rO1[ks], hb2, xq1);
            zhN = MFMA(rZh[ks], hb2, zhN);
            rhN = MFMA(rRh[ks], hb2, rhN);
        }
        st_bf4(XE, XE_STR, m, c0 * 2, xq0);
        st_bf4(XE, XE_STR, m, (c0 + 16) * 2, xq1);
        {
            float* xb = xs + ((size_t)m * NT + t) * NS;
            *(f32x4*)(xb + c0) = xq0;
            *(f32x4*)(xb + c0 + 16) = xq1;
        }
        zh = zhN; rh = rhN;
        cu0 = nx0; cu1 = nx1;
        SYNCW();  // bar D
    }
}

extern "C" void kernel_launch(void* const* d_in, const int* in_sizes, int n_in,
                              void* d_out, int out_size, void* d_ws, size_t ws_size,
                              hipStream_t stream) {
    (void)in_sizes; (void)n_in; (void)out_size; (void)ws_size;
    const float* x       = (const float*)d_in[0];
    const float* W_in    = (const float*)d_in[1];
    const float* b_in    = (const float*)d_in[2];
    const float* W_state = (const float*)d_in[3];
    const float* b_state = (const float*)d_in[4];
    const float* A       = (const float*)d_in[5];
    const float* H       = (const float*)d_in[6];
    const float* Q       = (const float*)d_in[7];
    const float* R       = (const float*)d_in[8];
    const float* W_z     = (const float*)d_in[9];
    const float* W_r     = (const float*)d_in[10];
    const float* W_h     = (const float*)d_in[11];
    const float* b_z     = (const float*)d_in[12];
    const float* b_r     = (const float*)d_in[13];
    const float* b_h     = (const float*)d_in[14];
    const float* W_out   = (const float*)d_in[15];
    const float* W_outp  = (const float*)d_in[16];
    const float* b_outp  = (const float*)d_in[17];
    float* out = (float*)d_out;
    float* w = (float*)d_ws;

    float* us   = w + OFF_US;
    float* Hu   = w + OFF_HU;
    float* u3   = w + OFF_U3;
    float* Kt   = w + OFF_KT;
    float* Ht   = w + OFF_HT;
    float* At   = w + OFF_AT;
    float* G    = w + OFF_G;
    float* IG   = w + OFF_IG;
    float* Minf = w + OFF_MINF;
    float* Wzt  = w + OFF_WZT;
    float* Wrt  = w + OFF_WRT;
    float* Wht  = w + OFF_WHT;
    float* HtWo = w + OFF_HTWO;
    short* pk   = (short*)(w + OFF_PACK);

    float* xs  = w + OFF_US;                 // aliases us in WS (round-10-validated): read-before-write
    float* usG = out + (size_t)4194304;      // d_out [4.19M..8.39M)
    float* u   = out + (size_t)8388608;      // d_out upper half (dead after us/Hu GEMMs)

    const int M = NB * NT;  // 16384

    hipLaunchKernelGGL(k_precompute, dim3(1), dim3(512), 0, stream, Q, R, Kt);
    hipLaunchKernelGGL(k_transpose, dim3((NS * NS + 255) / 256), dim3(256), 0, stream, A, At, NS, NS);
    hipLaunchKernelGGL(k_transpose, dim3((ND * NS + 255) / 256), dim3(256), 0, stream, H, Ht, ND, NS);
    hipLaunchKernelGGL(k_transpose, dim3((NH * 384 + 255) / 256), dim3(256), 0, stream, W_z, Wzt, NH, 384);
    hipLaunchKernelGGL(k_transpose, dim3((NH * 384 + 255) / 256), dim3(256), 0, stream, W_r, Wrt, NH, 384);
    hipLaunchKernelGGL(k_transpose, dim3((NH * 384 + 255) / 256), dim3(256), 0, stream, W_h, Wht, NH, 384);
    // exact f32 small GEMMs
    hipLaunchKernelGGL(k_gemm, dim3(NS / 64, NS / 64), dim3(256), 0, stream,
                       Ht, H, nullptr, nullptr, G, NS, NS, ND, 0);
    hipLaunchKernelGGL(k_gemm, dim3(NE / 64, NS / 64), dim3(256), 0, stream,
                       Ht, W_outp, nullptr, nullptr, HtWo, NS, NE, ND, 0);
    hipLaunchKernelGGL(k_ig, dim3(256), dim3(256), 0, stream, G, Kt, IG);
    hipLaunchKernelGGL(k_gemm, dim3(NS / 64, NS / 64), dim3(256), 0, stream,
                       At, IG, nullptr, nullptr, Minf, NS, NS, NS, 0);
    // weight packs
    hipLaunchKernelGGL(k_pack, dim3((NS * NS + 255) / 256), dim3(256), 0, stream, At, pk + PK_A, NS, NS);
    hipLaunchKernelGGL(k_pack, dim3((NS * NS + 255) / 256), dim3(256), 0, stream, G, pk + PK_G, NS, NS);
    hipLaunchKernelGGL(k_pack, dim3((NS * NS + 255) / 256), dim3(256), 0, stream, Minf, pk + PK_M, NS, NS);
    hipLaunchKernelGGL(k_pack, dim3((384 * NH + 255) / 256), dim3(256), 0, stream, Wzt, pk + PK_Z, 384, NH);
    hipLaunchKernelGGL(k_pack, dim3((384 * NH + 255) / 256), dim3(256), 0, stream, Wrt, pk + PK_R, 384, NH);
    hipLaunchKernelGGL(k_pack, dim3((384 * NH + 255) / 256), dim3(256), 0, stream, Wht, pk + PK_H, 384, NH);
    hipLaunchKernelGGL(k_pack, dim3((NH * NS + 255) / 256), dim3(256), 0, stream, W_out, pk + PK_O, NH, NS);
    hipLaunchKernelGGL(k_pack, dim3((NE * ND + 255) / 256), dim3(256), 0, stream, W_in, pk + PK_WIN, NE, ND);
    hipLaunchKernelGGL(k_pack, dim3((ND * NS + 255) / 256), dim3(256), 0, stream, W_state, pk + PK_WST, ND, NS);
    hipLaunchKernelGGL(k_pack, dim3((ND * NS + 255) / 256), dim3(256), 0, stream, H, pk + PK_HM, ND, NS);
    hipLaunchKernelGGL(k_pack, dim3((NS * NE + 255) / 256), dim3(256), 0, stream, HtWo, pk + PK_HTW, NS, NE);
    // u = gelu(x@W_in + b_in)
    hipLaunchKernelGGL(k_mm, dim3(M / 64, ND / 128), dim3(256), 0, stream,
                       x, pk + PK_WIN, b_in, nullptr, u, ND, NE, 1);
    // us, Hu
    hipLaunchKernelGGL(k_mm, dim3(M / 64, NS / 128), dim3(256), 0, stream,
                       u, pk + PK_WST, b_state, nullptr, us, NS, ND, 0);
    hipLaunchKernelGGL(k_mm, dim3(M / 64, NS / 128), dim3(256), 0, stream,
                       u, pk + PK_HM, nullptr, nullptr, Hu, NS, ND, 0);
    // usG = us@G ; u3 = us + K.*(Hu - usG)
    hipLaunchKernelGGL(k_mm, dim3(M / 64, NS / 128), dim3(256), 0, stream,
                       us, pk + PK_G, nullptr, nullptr, usG, NS, NS, 0);
    hipLaunchKernelGGL(k_fuse, dim3((NT * NB * NS) / 256), dim3(256), 0, stream,
                       us, usG, Hu, Kt, u3);
    // scan (xs overwrites us in place, ws; read-before-write per step)
    hipLaunchKernelGGL(k_scan_mfma, dim3(1), dim3(512), 0, stream,
                       pk + PK_M, pk + PK_A, pk + PK_G, pk + PK_Z, pk + PK_R, pk + PK_H,
                       pk + PK_O,
                       b_z, b_r, b_h, us, Hu, u3, Kt, xs);
    // out = xs@(Ht@W_outp) + b_outp + x   (xs in ws, out in d_out — disjoint)
    hipLaunchKernelGGL(k_mm, dim3(M / 64, NE / 128), dim3(256), 0, stream,
                       xs, pk + PK_HTW, b_outp, x, out, NE, NS, 0);
}

// Round 14
// 3257.612 us; speedup vs baseline: 1.5822x; 1.0855x over previous
//
#include <hip/hip_runtime.h>
#include <cstdint>
#include <cstddef>

// Problem dims
#define NB 16
#define NT 1024
#define NE 1024
#define NS 256
#define ND 512
#define NH 128
#define T0 16

// ---- ws layout (float offsets) ----
#define OFF_US   ((size_t)0)          // us [m][t][s]; scan overwrites in-place as xs
#define OFF_HU   ((size_t)4194304)
#define OFF_U3   ((size_t)8388608)
#define OFF_KT   ((size_t)12582912)
#define OFF_HT   ((size_t)12845056)
#define OFF_AT   ((size_t)12976128)
#define OFF_G    ((size_t)13041664)
#define OFF_IG   ((size_t)13107200)
#define OFF_MINF ((size_t)13172736)
#define OFF_WZT  ((size_t)13238272)
#define OFF_WRT  ((size_t)13287424)
#define OFF_WHT  ((size_t)13336576)
#define OFF_HTWO ((size_t)13385728)   // 256*1024
#define OFF_PACK ((size_t)13647872)   // 1425408 shorts -> ws end 14360576 fl (57.4MB)

// pack sub-offsets (shorts)
#define PK_A   0
#define PK_G   65536
#define PK_M   131072
#define PK_Z   196608
#define PK_R   245760
#define PK_H   294912
#define PK_O   344064
#define PK_WIN 376832
#define PK_WST 901120
#define PK_HM  1032192
#define PK_HTW 1163264

// d_out scratch (floats): usG [4.19M..8.39M); u f32 [8.39M..16.78M) (dead after us/Hu).
// Final GEMM reads xs from ws and overwrites all of d_out — disjoint.

typedef short bf16x8 __attribute__((ext_vector_type(8)));
typedef float f32x4 __attribute__((ext_vector_type(4)));
typedef unsigned int u32x2 __attribute__((ext_vector_type(2)));

#define MFMA(a, b, c) __builtin_amdgcn_mfma_f32_16x16x32_bf16((a), (b), (c), 0, 0, 0)

// barrier WITHOUT vmcnt drain
#define SYNCW() do { \
    __builtin_amdgcn_sched_barrier(0); \
    asm volatile("s_waitcnt lgkmcnt(0)" ::: "memory"); \
    __builtin_amdgcn_s_barrier(); \
    __builtin_amdgcn_sched_barrier(0); \
} while (0)

__device__ __forceinline__ float gelu_tanh(float v) {
    const float c = 0.7978845608028654f;
    float t = tanhf(c * (v + 0.044715f * v * v * v));
    return 0.5f * v * (1.0f + t);
}
__device__ __forceinline__ float softplus_f(float x) {
    if (x > 20.0f) return x;
    return log1pf(expf(x));
}
__device__ __forceinline__ short f2bf_s(float f) {
    unsigned u = __float_as_uint(f);
    u += 0x7fffu + ((u >> 16) & 1u);
    return (short)(u >> 16);
}
__device__ __forceinline__ unsigned pk_bf(float a, float b) {
    return ((unsigned)(unsigned short)f2bf_s(b) << 16) | (unsigned)(unsigned short)f2bf_s(a);
}
__device__ __forceinline__ float exp2_hw(float x) {
    float r; asm("v_exp_f32 %0, %1" : "=v"(r) : "v"(x)); return r;
}
__device__ __forceinline__ float rcp_hw(float x) {
    float r; asm("v_rcp_f32 %0, %1" : "=v"(r) : "v"(x)); return r;
}
__device__ __forceinline__ f32x4 sig4(f32x4 x) {
    f32x4 o;
#pragma unroll
    for (int i = 0; i < 4; ++i)
        o[i] = rcp_hw(1.0f + exp2_hw(-1.442695040888963f * x[i]));
    return o;
}
__device__ __forceinline__ f32x4 tanh4(f32x4 x) {
    f32x4 o;
#pragma unroll
    for (int i = 0; i < 4; ++i) {
        float e = exp2_hw(2.885390081777927f * x[i]);
        o[i] = 1.0f - 2.0f * rcp_hw(e + 1.0f);
    }
    return o;
}
__device__ __forceinline__ void st_bf4(char* base, int stride, int row, int byteoff,
                                       const f32x4& v) {
    u32x2 p;
    p[0] = pk_bf(v[0], v[1]);
    p[1] = pk_bf(v[2], v[3]);
    *(u32x2*)(base + row * stride + byteoff) = p;
}

#define BFRAG(buf, STR, ks) (*(const bf16x8*)((buf) + (l & 15) * (STR) + (ks) * 64 + (l >> 4) * 16))
#define GFRAG(p, fi) (*(const bf16x8*)((p) + ((size_t)(fi) * 64 + l) * 8))
#define LFRAG(buf, fi) (*(const bf16x8*)((buf) + (size_t)(fi) * 1024 + l * 16))

// ---- P/K covariance recurrence ----
__global__ __launch_bounds__(512) void k_precompute(const float* __restrict__ Q,
                                                    const float* __restrict__ R,
                                                    float* __restrict__ Kt) {
    __shared__ float red[512];
    __shared__ float r_eff_sh;
    const int t = threadIdx.x;
    red[t] = softplus_f(R[t]);
    __syncthreads();
    for (int s = 256; s > 0; s >>= 1) {
        if (t < s) red[t] += red[t + s];
        __syncthreads();
    }
    if (t == 0) r_eff_sh = red[0] / 512.0f;
    __syncthreads();
    const float r_eff = r_eff_sh;
    if (t < NS) {
        const float q = softplus_f(Q[t]);
        float P = 1.0f;
        for (int step = 0; step < NT; ++step) {
            float Pp = fminf(fmaxf(P + q, 1e-6f), 10.0f);
            float K  = fminf(fmaxf(Pp / (Pp + r_eff + 1e-6f), 0.0f), 1.0f);
            Kt[(size_t)step * NS + t] = K;
            P = fminf(fmaxf(Pp * (1.0f - K), 1e-6f), 10.0f);
        }
    }
}

__global__ void k_transpose(const float* __restrict__ in, float* __restrict__ outp,
                            int Rr, int Cc) {
    int i = blockIdx.x * 256 + threadIdx.x;
    if (i < Rr * Cc) {
        int r = i / Cc, c = i % Cc;
        outp[(size_t)c * Rr + r] = in[i];
    }
}

__global__ void k_ig(const float* __restrict__ G, const float* __restrict__ Kt,
                     float* __restrict__ IG) {
    int i = blockIdx.x * 256 + threadIdx.x;
    if (i >= NS * NS) return;
    int r = i >> 8, c = i & 255;
    float kinf = Kt[(size_t)(NT - 1) * NS + c];
    IG[i] = ((r == c) ? 1.0f : 0.0f) - G[i] * kinf;
}

__global__ void k_fuse(const float* __restrict__ us, const float* __restrict__ usG,
                       const float* __restrict__ Hu, const float* __restrict__ Kt,
                       float* __restrict__ u3) {
    int i = blockIdx.x * 256 + threadIdx.x;
    if (i >= NT * NB * NS) return;
    int s = i & 255;
    int tm = i >> 8;
    int m = tm & 15, t = tm >> 4;
    size_t src = ((size_t)m * NT + t) * NS + s;
    float k = Kt[(size_t)t * NS + s];
    u3[i] = us[src] + k * (Hu[src] - usG[src]);
}

// ---- pack W[K][N] f32 -> bf16 B-operand frags ----
__global__ void k_pack(const float* __restrict__ W, short* __restrict__ dst, int K, int N) {
    int f = blockIdx.x * 256 + threadIdx.x;
    if (f >= K * N) return;
    const int j = f & 7, l = (f >> 3) & 63, tile = f >> 9;
    const int KS = K >> 5;
    const int nt = tile / KS, ks = tile - nt * KS;
    const int k = ks * 32 + (l >> 4) * 8 + j;
    const int n = nt * 16 + (l & 15);
    dst[f] = f2bf_s(W[(size_t)k * N + n]);
}

// ---- bf16 MFMA GEMM with fused f32->bf16 A conversion ----
__global__ __launch_bounds__(256) void k_mm(const float* __restrict__ Af,
                                            const short* __restrict__ Bpk,
                                            const float* __restrict__ bias,
                                            const float* __restrict__ resid,
                                            float* __restrict__ C,
                                            int N, int K, int act) {
    const int tid = threadIdx.x, w = tid >> 6, l = tid & 63;
    const int KS = K >> 5;
    const int mt = blockIdx.x * 4 + w;
    const int nt0 = blockIdx.y * 8;
    const float* arow = Af + (size_t)(mt * 16 + (l & 15)) * K + ((l >> 4) * 8);
    f32x4 acc[8];
#pragma unroll
    for (int j = 0; j < 8; ++j) acc[j] = (f32x4){0.f, 0.f, 0.f, 0.f};
    for (int ks = 0; ks < KS; ++ks) {
        const float* ap = arow + ks * 32;
        f32x4 a0 = *(const f32x4*)ap;
        f32x4 a1 = *(const f32x4*)(ap + 4);
        union { bf16x8 v; unsigned u[4]; } au;
        au.u[0] = pk_bf(a0[0], a0[1]); au.u[1] = pk_bf(a0[2], a0[3]);
        au.u[2] = pk_bf(a1[0], a1[1]); au.u[3] = pk_bf(a1[2], a1[3]);
#pragma unroll
        for (int j = 0; j < 8; ++j) {
            bf16x8 b = *(const bf16x8*)(Bpk + ((size_t)(nt0 + j) * KS + ks) * 512 + (size_t)l * 8);
            acc[j] = MFMA(b, au.v, acc[j]);
        }
    }
    const int m = mt * 16 + (l & 15);
    const int lg = l >> 4;
#pragma unroll
    for (int j = 0; j < 8; ++j) {
        const int n = (nt0 + j) * 16 + lg * 4;
        f32x4 v = acc[j];
        if (bias) v += *(const f32x4*)(bias + n);
        if (act) {
#pragma unroll
            for (int r = 0; r < 4; ++r) v[r] = gelu_tanh(v[r]);
        }
        if (resid) v += *(const f32x4*)(resid + (size_t)m * N + n);
        *(f32x4*)(C + (size_t)m * N + n) = v;
    }
}

// ---- f32 tiled GEMM (small exact matrices) ----
__global__ __launch_bounds__(256) void k_gemm(const float* __restrict__ Am,
                                              const float* __restrict__ Bm,
                                              const float* __restrict__ bias,
                                              const float* __restrict__ resid,
                                              float* __restrict__ Cm,
                                              int M, int N, int K, int act) {
    __shared__ __align__(16) float As[16][68];
    __shared__ __align__(16) float Bs[16][68];
    const int tid = threadIdx.x;
    const int bn = blockIdx.x, bm = blockIdx.y;
    const int row0 = bm * 64, col0 = bn * 64;
    const int tx = tid & 15, ty = tid >> 4;
    const int ar = tid >> 2, ac = (tid & 3) << 2;
    const int bk = tid >> 4, bc = (tid & 15) << 2;

    float acc[4][4];
#pragma unroll
    for (int i = 0; i < 4; ++i)
#pragma unroll
        for (int j = 0; j < 4; ++j) acc[i][j] = 0.0f;

    for (int k0 = 0; k0 < K; k0 += 16) {
        float4 av = *(const float4*)(Am + (size_t)(row0 + ar) * K + k0 + ac);
        float4 bv = *(const float4*)(Bm + (size_t)(k0 + bk) * N + col0 + bc);
        As[ac + 0][ar] = av.x; As[ac + 1][ar] = av.y;
        As[ac + 2][ar] = av.z; As[ac + 3][ar] = av.w;
        *(float4*)&Bs[bk][bc] = bv;
        __syncthreads();
#pragma unroll
        for (int kk = 0; kk < 16; ++kk) {
            const float a0 = As[kk][ty * 4 + 0], a1 = As[kk][ty * 4 + 1];
            const float a2 = As[kk][ty * 4 + 2], a3 = As[kk][ty * 4 + 3];
            const float4 b4 = *(const float4*)&Bs[kk][tx * 4];
            acc[0][0] += a0 * b4.x; acc[0][1] += a0 * b4.y; acc[0][2] += a0 * b4.z; acc[0][3] += a0 * b4.w;
            acc[1][0] += a1 * b4.x; acc[1][1] += a1 * b4.y; acc[1][2] += a1 * b4.z; acc[1][3] += a1 * b4.w;
            acc[2][0] += a2 * b4.x; acc[2][1] += a2 * b4.y; acc[2][2] += a2 * b4.z; acc[2][3] += a2 * b4.w;
            acc[3][0] += a3 * b4.x; acc[3][1] += a3 * b4.y; acc[3][2] += a3 * b4.z; acc[3][3] += a3 * b4.w;
        }
        __syncthreads();
    }
#pragma unroll
    for (int i = 0; i < 4; ++i) {
        const int r = row0 + ty * 4 + i;
#pragma unroll
        for (int j = 0; j < 4; ++j) {
            const int c = col0 + tx * 4 + j;
            float v = acc[i][j];
            if (bias) v += bias[c];
            if (act) v = gelu_tanh(v);
            if (resid) v += resid[(size_t)r * N + c];
            Cm[(size_t)r * N + c] = v;
        }
    }
}

// ===================== MFMA scan (round-9 structure; in-step u3 loads) =====================
#define XE_STR 528
#define HB_STR 272

__global__ __launch_bounds__(512, 2) void k_scan_mfma(
    const short* __restrict__ pM, const short* __restrict__ pA, const short* __restrict__ pG,
    const short* __restrict__ pZ, const short* __restrict__ pR, const short* __restrict__ pH,
    const short* __restrict__ pO,
    const float* __restrict__ bz, const float* __restrict__ br, const float* __restrict__ bh,
    const float* __restrict__ us, const float* __restrict__ Hu, const float* __restrict__ u3,
    const float* __restrict__ Kt, float* __restrict__ xs)
{
    __shared__ __align__(16) char XE[16 * XE_STR];
    __shared__ __align__(16) char XT[16 * XE_STR];
    __shared__ __align__(16) char HBs[16 * HB_STR];
    __shared__ __align__(16) char RGs[16 * HB_STR];
    __shared__ __align__(16) char WHH[96 * 1024];

    const int tid = threadIdx.x, w = tid >> 6, l = tid & 63;
    const int m = l & 15, lg = l >> 4;
    const int c0 = 32 * w + 4 * lg;
    const int cg = 16 * w + 4 * lg;

    for (int i = tid; i < (16 * XE_STR) / 4; i += 512) ((int*)XE)[i] = 0;
    for (int i = tid; i < (16 * HB_STR) / 4; i += 512) ((int*)HBs)[i] = 0;
    for (int i = tid; i < 6144; i += 512) ((int4*)WHH)[i] = ((const int4*)pH)[i];

    const f32x4 bzv = *(const f32x4*)(bz + cg);
    const f32x4 brv = *(const f32x4*)(br + cg);
    const f32x4 bhv = *(const f32x4*)(bh + cg);
    f32x4 hFr = {0.f, 0.f, 0.f, 0.f};
    __syncthreads();

    // ------------- early phase t<T0 (exact per-t K, streamed weights) -------------
    for (int t = 0; t < T0; ++t) {
        const float* usb = us + ((size_t)m * NT + t) * NS;
        const float* hub = Hu + ((size_t)m * NT + t) * NS;
        const float* ktb = Kt + (size_t)t * NS;
        f32x4 us0 = *(const f32x4*)(usb + c0), us1 = *(const f32x4*)(usb + c0 + 16);
        f32x4 hu0 = *(const f32x4*)(hub + c0), hu1 = *(const f32x4*)(hub + c0 + 16);
        f32x4 kv0 = *(const f32x4*)(ktb + c0), kv1 = *(const f32x4*)(ktb + c0 + 16);
        f32x4 p0 = {0.f,0.f,0.f,0.f}, p1 = {0.f,0.f,0.f,0.f};
#pragma unroll
        for (int ks = 0; ks < 8; ++ks) {
            bf16x8 xe = BFRAG(XE, XE_STR, ks);
            p0 = MFMA(GFRAG(pA, (2 * w + 0) * 8 + ks), xe, p0);
            p1 = MFMA(GFRAG(pA, (2 * w + 1) * 8 + ks), xe, p1);
        }
        p0 += us0; p1 += us1;
        st_bf4(XT, XE_STR, m, c0 * 2, p0);
        st_bf4(XT, XE_STR, m, (c0 + 16) * 2, p1);
        SYNCW();
        f32x4 g0 = {0.f,0.f,0.f,0.f}, g1 = {0.f,0.f,0.f,0.f};
#pragma unroll
        for (int ks = 0; ks < 8; ++ks) {
            bf16x8 xt = BFRAG(XT, XE_STR, ks);
            g0 = MFMA(GFRAG(pG, (2 * w + 0) * 8 + ks), xt, g0);
            g1 = MFMA(GFRAG(pG, (2 * w + 1) * 8 + ks), xt, g1);
        }
        f32x4 xq0 = p0 + kv0 * (hu0 - g0);
        f32x4 xq1 = p1 + kv1 * (hu1 - g1);
        st_bf4(XE, XE_STR, m, c0 * 2, xq0);
        st_bf4(XE, XE_STR, m, (c0 + 16) * 2, xq1);
        SYNCW();
        f32x4 za = bzv, ra = brv, hx = bhv;
#pragma unroll
        for (int ks = 0; ks < 4; ++ks) {
            bf16x8 hb = BFRAG(HBs, HB_STR, ks);
            za = MFMA(GFRAG(pZ, w * 12 + ks), hb, za);
            ra = MFMA(GFRAG(pR, w * 12 + ks), hb, ra);
        }
#pragma unroll
        for (int ks = 0; ks < 8; ++ks) {
            bf16x8 xef = BFRAG(XE, XE_STR, ks);
            za = MFMA(GFRAG(pZ, w * 12 + 4 + ks), xef, za);
            ra = MFMA(GFRAG(pR, w * 12 + 4 + ks), xef, ra);
            hx = MFMA(GFRAG(pH, w * 12 + 4 + ks), xef, hx);
        }
        f32x4 z = sig4(za), r = sig4(ra), rg = r * hFr;
        st_bf4(RGs, HB_STR, m, cg * 2, rg);
        SYNCW();
        f32x4 hc = hx;
#pragma unroll
        for (int ks = 0; ks < 4; ++ks)
            hc = MFMA(GFRAG(pH, w * 12 + ks), BFRAG(RGs, HB_STR, ks), hc);
        f32x4 hcv = tanh4(hc);
        f32x4 hn = hFr + z * (hcv - hFr);
        hFr = hn;
        st_bf4(HBs, HB_STR, m, cg * 2, hn);
        SYNCW();
#pragma unroll
        for (int ks = 0; ks < 4; ++ks) {
            bf16x8 hb2 = BFRAG(HBs, HB_STR, ks);
            xq0 = MFMA(GFRAG(pO, (2 * w + 0) * 4 + ks), hb2, xq0);
            xq1 = MFMA(GFRAG(pO, (2 * w + 1) * 4 + ks), hb2, xq1);
        }
        st_bf4(XE, XE_STR, m, c0 * 2, xq0);
        st_bf4(XE, XE_STR, m, (c0 + 16) * 2, xq1);
        {
            float* xb = xs + ((size_t)m * NT + t) * NS;
            *(f32x4*)(xb + c0) = xq0;
            *(f32x4*)(xb + c0 + 16) = xq1;
        }
        SYNCW();
    }

    // ------------- register weights for main loop (192 static, validated) -------------
    bf16x8 rM0[8], rM1[8], rZx[8], rRx[8], rZh[4], rRh[4], rO0[4], rO1[4];
#pragma unroll
    for (int ks = 0; ks < 8; ++ks) {
        rM0[ks] = GFRAG(pM, (2 * w + 0) * 8 + ks);
        rM1[ks] = GFRAG(pM, (2 * w + 1) * 8 + ks);
        rZx[ks] = GFRAG(pZ, w * 12 + 4 + ks);
        rRx[ks] = GFRAG(pR, w * 12 + 4 + ks);
    }
#pragma unroll
    for (int ks = 0; ks < 4; ++ks) {
        rZh[ks] = GFRAG(pZ, w * 12 + ks);
        rRh[ks] = GFRAG(pR, w * 12 + ks);
        rO0[ks] = GFRAG(pO, (2 * w + 0) * 4 + ks);
        rO1[ks] = GFRAG(pO, (2 * w + 1) * 4 + ks);
    }

    f32x4 zh = bzv, rh = brv;
#pragma unroll
    for (int ks = 0; ks < 4; ++ks) {
        bf16x8 hb = BFRAG(HBs, HB_STR, ks);
        zh = MFMA(rZh[ks], hb, zh);
        rh = MFMA(rRh[ks], hb, rh);
    }

    // ------------- main loop: 4 barriers/step (round-9 in-step u3 loads) -------------
    for (int t = T0; t < NT; ++t) {
        const float* ubase = u3 + ((size_t)(t * NB) + m) * NS;
        f32x4 cu0 = *(const f32x4*)(ubase + c0);
        f32x4 cu1 = *(const f32x4*)(ubase + c0 + 16);

        f32x4 xq0 = {0.f,0.f,0.f,0.f}, xq1 = {0.f,0.f,0.f,0.f};
#pragma unroll
        for (int ks = 0; ks < 8; ++ks) {
            bf16x8 xe = BFRAG(XE, XE_STR, ks);
            xq0 = MFMA(rM0[ks], xe, xq0);
            xq1 = MFMA(rM1[ks], xe, xq1);
        }
        xq0 += cu0; xq1 += cu1;
        st_bf4(XT, XE_STR, m, c0 * 2, xq0);
        st_bf4(XT, XE_STR, m, (c0 + 16) * 2, xq1);
        SYNCW();  // bar A
        f32x4 za = zh, ra = rh, hx = bhv;
#pragma unroll
        for (int ks = 0; ks < 8; ++ks) {
            bf16x8 xt = BFRAG(XT, XE_STR, ks);
            za = MFMA(rZx[ks], xt, za);
            ra = MFMA(rRx[ks], xt, ra);
            hx = MFMA(LFRAG(WHH, w * 12 + 4 + ks), xt, hx);
        }
        f32x4 z = sig4(za), r = sig4(ra), rg = r * hFr;
        st_bf4(RGs, HB_STR, m, cg * 2, rg);
        SYNCW();  // bar B
        f32x4 hc = hx;
#pragma unroll
        for (int ks = 0; ks < 4; ++ks)
            hc = MFMA(LFRAG(WHH, w * 12 + ks), BFRAG(RGs, HB_STR, ks), hc);
        f32x4 hcv = tanh4(hc);
        f32x4 hn = hFr + z * (hcv - hFr);
        hFr = hn;
        st_bf4(HBs, HB_STR, m, cg * 2, hn);
        SYNCW();  // bar C
        f32x4 zhN = bzv, rhN = brv;
#pragma unroll
        for (int ks = 0; ks < 4; ++ks) {
            bf16x8 hb2 = BFRAG(HBs, HB_STR, ks);
            xq0 = MFMA(rO0[ks], hb2, xq0);
            xq1 = MFMA(rO1[ks], hb2, xq1);
            zhN = MFMA(rZh[ks], hb2, zhN);
            rhN = MFMA(rRh[ks], hb2, rhN);
        }
        st_bf4(XE, XE_STR, m, c0 * 2, xq0);
        st_bf4(XE, XE_STR, m, (c0 + 16) * 2, xq1);
        {
            float* xb = xs + ((size_t)m * NT + t) * NS;
            *(f32x4*)(xb + c0) = xq0;
            *(f32x4*)(xb + c0 + 16) = xq1;
        }
        zh = zhN; rh = rhN;
        SYNCW();  // bar D
    }
}

extern "C" void kernel_launch(void* const* d_in, const int* in_sizes, int n_in,
                              void* d_out, int out_size, void* d_ws, size_t ws_size,
                              hipStream_t stream) {
    (void)in_sizes; (void)n_in; (void)out_size; (void)ws_size;
    const float* x       = (const float*)d_in[0];
    const float* W_in    = (const float*)d_in[1];
    const float* b_in    = (const float*)d_in[2];
    const float* W_state = (const float*)d_in[3];
    const float* b_state = (const float*)d_in[4];
    const float* A       = (const float*)d_in[5];
    const float* H       = (const float*)d_in[6];
    const float* Q       = (const float*)d_in[7];
    const float* R       = (const float*)d_in[8];
    const float* W_z     = (const float*)d_in[9];
    const float* W_r     = (const float*)d_in[10];
    const float* W_h     = (const float*)d_in[11];
    const float* b_z     = (const float*)d_in[12];
    const float* b_r     = (const float*)d_in[13];
    const float* b_h     = (const float*)d_in[14];
    const float* W_out   = (const float*)d_in[15];
    const float* W_outp  = (const float*)d_in[16];
    const float* b_outp  = (const float*)d_in[17];
    float* out = (float*)d_out;
    float* w = (float*)d_ws;

    float* us   = w + OFF_US;
    float* Hu   = w + OFF_HU;
    float* u3   = w + OFF_U3;
    float* Kt   = w + OFF_KT;
    float* Ht   = w + OFF_HT;
    float* At   = w + OFF_AT;
    float* G    = w + OFF_G;
    float* IG   = w + OFF_IG;
    float* Minf = w + OFF_MINF;
    float* Wzt  = w + OFF_WZT;
    float* Wrt  = w + OFF_WRT;
    float* Wht  = w + OFF_WHT;
    float* HtWo = w + OFF_HTWO;
    short* pk   = (short*)(w + OFF_PACK);

    float* xs  = w + OFF_US;                 // aliases us in WS (validated): read-before-write
    float* usG = out + (size_t)4194304;      // d_out [4.19M..8.39M)
    float* u   = out + (size_t)8388608;      // d_out upper half (dead after us/Hu GEMMs)

    const int M = NB * NT;  // 16384

    hipLaunchKernelGGL(k_precompute, dim3(1), dim3(512), 0, stream, Q, R, Kt);
    hipLaunchKernelGGL(k_transpose, dim3((NS * NS + 255) / 256), dim3(256), 0, stream, A, At, NS, NS);
    hipLaunchKernelGGL(k_transpose, dim3((ND * NS + 255) / 256), dim3(256), 0, stream, H, Ht, ND, NS);
    hipLaunchKernelGGL(k_transpose, dim3((NH * 384 + 255) / 256), dim3(256), 0, stream, W_z, Wzt, NH, 384);
    hipLaunchKernelGGL(k_transpose, dim3((NH * 384 + 255) / 256), dim3(256), 0, stream, W_r, Wrt, NH, 384);
    hipLaunchKernelGGL(k_transpose, dim3((NH * 384 + 255) / 256), dim3(256), 0, stream, W_h, Wht, NH, 384);
    // exact f32 small GEMMs
    hipLaunchKernelGGL(k_gemm, dim3(NS / 64, NS / 64), dim3(256), 0, stream,
                       Ht, H, nullptr, nullptr, G, NS, NS, ND, 0);
    hipLaunchKernelGGL(k_gemm, dim3(NE / 64, NS / 64), dim3(256), 0, stream,
                       Ht, W_outp, nullptr, nullptr, HtWo, NS, NE, ND, 0);
    hipLaunchKernelGGL(k_ig, dim3(256), dim3(256), 0, stream, G, Kt, IG);
    hipLaunchKernelGGL(k_gemm, dim3(NS / 64, NS / 64), dim3(256), 0, stream,
                       At, IG, nullptr, nullptr, Minf, NS, NS, NS, 0);
    // weight packs
    hipLaunchKernelGGL(k_pack, dim3((NS * NS + 255) / 256), dim3(256), 0, stream, At, pk + PK_A, NS, NS);
    hipLaunchKernelGGL(k_pack, dim3((NS * NS + 255) / 256), dim3(256), 0, stream, G, pk + PK_G, NS, NS);
    hipLaunchKernelGGL(k_pack, dim3((NS * NS + 255) / 256), dim3(256), 0, stream, Minf, pk + PK_M, NS, NS);
    hipLaunchKernelGGL(k_pack, dim3((384 * NH + 255) / 256), dim3(256), 0, stream, Wzt, pk + PK_Z, 384, NH);
    hipLaunchKernelGGL(k_pack, dim3((384 * NH + 255) / 256), dim3(256), 0, stream, Wrt, pk + PK_R, 384, NH);
    hipLaunchKernelGGL(k_pack, dim3((384 * NH + 255) / 256), dim3(256), 0, stream, Wht, pk + PK_H, 384, NH);
    hipLaunchKernelGGL(k_pack, dim3((NH * NS + 255) / 256), dim3(256), 0, stream, W_out, pk + PK_O, NH, NS);
    hipLaunchKernelGGL(k_pack, dim3((NE * ND + 255) / 256), dim3(256), 0, stream, W_in, pk + PK_WIN, NE, ND);
    hipLaunchKernelGGL(k_pack, dim3((ND * NS + 255) / 256), dim3(256), 0, stream, W_state, pk + PK_WST, ND, NS);
    hipLaunchKernelGGL(k_pack, dim3((ND * NS + 255) / 256), dim3(256), 0, stream, H, pk + PK_HM, ND, NS);
    hipLaunchKernelGGL(k_pack, dim3((NS * NE + 255) / 256), dim3(256), 0, stream, HtWo, pk + PK_HTW, NS, NE);
    // u = gelu(x@W_in + b_in)
    hipLaunchKernelGGL(k_mm, dim3(M / 64, ND / 128), dim3(256), 0, stream,
                       x, pk + PK_WIN, b_in, nullptr, u, ND, NE, 1);
    // us, Hu
    hipLaunchKernelGGL(k_mm, dim3(M / 64, NS / 128), dim3(256), 0, stream,
                       u, pk + PK_WST, b_state, nullptr, us, NS, ND, 0);
    hipLaunchKernelGGL(k_mm, dim3(M / 64, NS / 128), dim3(256), 0, stream,
                       u, pk + PK_HM, nullptr, nullptr, Hu, NS, ND, 0);
    // usG = us@G ; u3 = us + K.*(Hu - usG)
    hipLaunchKernelGGL(k_mm, dim3(M / 64, NS / 128), dim3(256), 0, stream,
                       us, pk + PK_G, nullptr, nullptr, usG, NS, NS, 0);
    hipLaunchKernelGGL(k_fuse, dim3((NT * NB * NS) / 256), dim3(256), 0, stream,
                       us, usG, Hu, Kt, u3);
    // scan (xs overwrites us in place, ws; read-before-write per step)
    hipLaunchKernelGGL(k_scan_mfma, dim3(1), dim3(512), 0, stream,
                       pk + PK_M, pk + PK_A, pk + PK_G, pk + PK_Z, pk + PK_R, pk + PK_H,
                       pk + PK_O,
                       b_z, b_r, b_h, us, Hu, u3, Kt, xs);
    // out = xs@(Ht@W_outp) + b_outp + x   (xs in ws, out in d_out — disjoint)
    hipLaunchKernelGGL(k_mm, dim3(M / 64, NE / 128), dim3(256), 0, stream,
                       xs, pk + PK_HTW, b_outp, x, out, NE, NS, 0);
}